// Round 1
// baseline (1677.642 us; speedup 1.0000x reference)
//
#include <hip/hip_runtime.h>
#include <hip/hip_bf16.h>
#include <hip/hip_fp16.h>
#include <math.h>

#define B_ 256
#define C1_ 64
#define C2_ 128
#define T_ 256
#define H_ 256
#define EPS_ 1e-5f

typedef short short8 __attribute__((ext_vector_type(8)));
typedef float f32x4 __attribute__((ext_vector_type(4)));
typedef unsigned long long u64;

// ---------------- ws layout (bytes) ----------------
#define OFF_FLAGS 0              // 256 * 4
#define OFF_SC1   4096           // 64 f32
#define OFF_SH1   (4096 + 256)
#define OFF_SC2   (4096 + 512)   // 128 f32
#define OFF_SH2   (4096 + 1024)
#define OFF_PART1 8192           // 256*64*2*4 = 131072
#define OFF_PART2 139264         // 8192*64*2*4 = 4194304
#define OFF_Y2    4333568        // 256*128*256*2 = 16777216 (f16)
#define OFF_SEQ   21110784       // 16777216 (f16)
#define OFF_H0    37888000       // 2*256*256*2 = 262144 (f16)
#define OFF_H1    38150144       // 262144
#define OFF_HF    38412288       // 256*256*4 = 262144 (f32)

__device__ __forceinline__ unsigned short f2h(float f) {
  return __half_as_ushort(__float2half(f));
}
__device__ __forceinline__ float h2f(unsigned short u) {
  return __half2float(__ushort_as_half(u));
}
__device__ __forceinline__ float sigf(float x) { return 1.f / (1.f + __expf(-x)); }
__device__ __forceinline__ float tanhfast(float x) {
  return 1.f - 2.f / (__expf(2.f * x) + 1.f);
}

// ---------------- init: zero flags + h ping-pong buffers ----------------
__global__ void k_init(int* flags, u64* hz) {
  int t = blockIdx.x * blockDim.x + threadIdx.x;
  if (t < 256) flags[t] = 0;
  for (int i = t; i < 65536; i += 16384) hz[i] = 0ULL;  // 524288 B
}

// ---------------- conv1 + relu + pool4, BN1 partial stats ----------------
__global__ __launch_bounds__(256, 2) void k_conv1(const float* __restrict__ x,
                                                  const float* __restrict__ w1,
                                                  const float* __restrict__ b1,
                                                  float* __restrict__ part1) {
  __shared__ float xs[4104];
  __shared__ float w1s[576];
  __shared__ float b1s[64];
  __shared__ float red[64][4][2];
  const int tid = threadIdx.x, b = blockIdx.x;
  for (int j = tid; j < 4104; j += 256) {
    int p = j - 4;
    xs[j] = (p >= 0 && p < 4096) ? x[b * 4096 + p] : 0.f;
  }
  for (int j = tid; j < 576; j += 256) w1s[j] = w1[j];
  if (tid < 64) b1s[tid] = b1[tid];
  __syncthreads();
  const int c = tid >> 2, lq = tid & 3;
  float wr[9];
#pragma unroll
  for (int k = 0; k < 9; k++) wr[k] = w1s[c * 9 + k];
  const float bb = b1s[c];
  float S = 0.f, SS = 0.f;
  for (int li = 0; li < 256; li++) {
    int l = lq * 256 + li;
    int base = 4 * l;  // xs[j] = x[j-4]; input x[4l+jj-4+k] = xs[4l+jj+k]
    float a4 = 0.f;
#pragma unroll
    for (int jj = 0; jj < 4; jj++) {
      float cv = bb;
#pragma unroll
      for (int k = 0; k < 9; k++) cv += xs[base + jj + k] * wr[k];
      a4 += fmaxf(cv, 0.f);
    }
    float y = 0.25f * a4;
    S += y;
    SS += y * y;
  }
  red[c][lq][0] = S;
  red[c][lq][1] = SS;
  __syncthreads();
  if (tid < 64) {
    float s = 0.f, ss = 0.f;
#pragma unroll
    for (int q = 0; q < 4; q++) {
      s += red[tid][q][0];
      ss += red[tid][q][1];
    }
    part1[(b * 64 + tid) * 2 + 0] = s;
    part1[(b * 64 + tid) * 2 + 1] = ss;
  }
}

// ---------------- BN1 finalize ----------------
__global__ void k_bn1(const float* __restrict__ part1, const float* __restrict__ g,
                      const float* __restrict__ bt, float* __restrict__ sc,
                      float* __restrict__ sh) {
  __shared__ float rs[256], rss[256];
  const int c = blockIdx.x, tid = threadIdx.x;
  rs[tid] = part1[(tid * 64 + c) * 2 + 0];
  rss[tid] = part1[(tid * 64 + c) * 2 + 1];
  __syncthreads();
  for (int st = 128; st > 0; st >>= 1) {
    if (tid < st) {
      rs[tid] += rs[tid + st];
      rss[tid] += rss[tid + st];
    }
    __syncthreads();
  }
  if (tid == 0) {
    const float N = 256.f * 1024.f;
    float mean = rs[0] / N;
    float var = rss[0] / N - mean * mean;
    float scale = g[c] * rsqrtf(var + EPS_);
    sc[c] = scale;
    sh[c] = bt[c] - mean * scale;
  }
}

// ---------------- conv2 (recomputes conv1+bn1 on the fly) ----------------
// grid: b(256) x slice(16) x ohalf(2) = 8192 blocks
__global__ __launch_bounds__(256, 2) void k_conv2(
    const float* __restrict__ x, const float* __restrict__ w1,
    const float* __restrict__ b1, const float* __restrict__ sc1,
    const float* __restrict__ sh1, const float* __restrict__ w2,
    const float* __restrict__ b2, unsigned short* __restrict__ y2,
    float* __restrict__ part2) {
  __shared__ float xs[288];
  __shared__ float y1n[64][68];
  __shared__ unsigned short w2s[64 * 5 * 64];
  __shared__ float w1s[576], b1s[64], s1s[64], h1s[64], b2s[64];
  __shared__ float red[64][4][2];
  const int tid = threadIdx.x;
  const int bid = blockIdx.x;
  const int oh = bid & 1, slice = (bid >> 1) & 15, b = bid >> 5;
  const int l0 = slice * 64;
  for (int j = tid; j < 288; j += 256) {
    int p = 4 * l0 - 12 + j;
    xs[j] = (p >= 0 && p < 4096) ? x[b * 4096 + p] : 0.f;
  }
  for (int j = tid; j < 576; j += 256) w1s[j] = w1[j];
  if (tid < 64) {
    b1s[tid] = b1[tid];
    s1s[tid] = sc1[tid];
    h1s[tid] = sh1[tid];
    b2s[tid] = b2[oh * 64 + tid];
  }
  for (int j = tid; j < 64 * 5 * 64; j += 256) {
    int ol = j & 63, ik = j >> 6;
    int i = ik / 5, k = ik - i * 5;
    w2s[j] = f2h(w2[(oh * 64 + ol) * 320 + i * 5 + k]);
  }
  __syncthreads();
  // y1n[i][lw], lw 0..67 <-> l = l0-2+lw ; zero outside [0,1024)
  for (int j = tid; j < 64 * 68; j += 256) {
    int lw = j % 68, i = j / 68;
    int l = l0 - 2 + lw;
    float v = 0.f;
    if (l >= 0 && l < 1024) {
      float a4 = 0.f;
#pragma unroll
      for (int jj = 0; jj < 4; jj++) {
        float cv = b1s[i];
#pragma unroll
        for (int k = 0; k < 9; k++) cv += xs[4 * lw + jj + k] * w1s[i * 9 + k];
        a4 += fmaxf(cv, 0.f);
      }
      v = 0.25f * a4 * s1s[i] + h1s[i];
    }
    y1n[i][lw] = v;
  }
  __syncthreads();
  const int ol = tid & 63, lh = tid >> 6;  // lh 0..3, 16 output l's each
  float acc[16];
#pragma unroll
  for (int u = 0; u < 16; u++) acc[u] = 0.f;
  for (int i = 0; i < 64; i++) {
    float xr[20];
#pragma unroll
    for (int q = 0; q < 5; q++) {
      float4 tv = *(const float4*)&y1n[i][lh * 16 + q * 4];
      xr[q * 4 + 0] = tv.x;
      xr[q * 4 + 1] = tv.y;
      xr[q * 4 + 2] = tv.z;
      xr[q * 4 + 3] = tv.w;
    }
#pragma unroll
    for (int k = 0; k < 5; k++) {
      float wv = h2f(w2s[(i * 5 + k) * 64 + ol]);
#pragma unroll
      for (int u = 0; u < 16; u++) acc[u] += xr[u + k] * wv;
    }
  }
  const float b2v = b2s[ol];
  float yo[4];
  float S = 0.f, SS = 0.f;
#pragma unroll
  for (int tt = 0; tt < 4; tt++) {
    float sum = 0.f;
#pragma unroll
    for (int j = 0; j < 4; j++) sum += fmaxf(acc[tt * 4 + j] + b2v, 0.f);
    yo[tt] = 0.25f * sum;
    S += yo[tt];
    SS += yo[tt] * yo[tt];
  }
  {
    unsigned short pk0 = f2h(yo[0]), pk1 = f2h(yo[1]), pk2 = f2h(yo[2]), pk3 = f2h(yo[3]);
    u64 pv = (u64)pk0 | ((u64)pk1 << 16) | ((u64)pk2 << 32) | ((u64)pk3 << 48);
    int o = oh * 64 + ol;
    *(u64*)(y2 + (b * 128 + o) * 256 + slice * 16 + lh * 4) = pv;
  }
  red[ol][lh][0] = S;
  red[ol][lh][1] = SS;
  __syncthreads();
  if (tid < 64) {
    float s = 0.f, ss = 0.f;
#pragma unroll
    for (int q = 0; q < 4; q++) {
      s += red[tid][q][0];
      ss += red[tid][q][1];
    }
    part2[(bid * 64 + tid) * 2 + 0] = s;
    part2[(bid * 64 + tid) * 2 + 1] = ss;
  }
}

// ---------------- BN2 finalize ----------------
__global__ void k_bn2(const float* __restrict__ part2, const float* __restrict__ g,
                      const float* __restrict__ bt, float* __restrict__ sc,
                      float* __restrict__ sh) {
  __shared__ float rs[256], rss[256];
  const int o = blockIdx.x, tid = threadIdx.x;
  const int oh = o >> 6, ol = o & 63;
  float s = 0.f, ss = 0.f;
  for (int q = 0; q < 16; q++) {
    int bs = tid + q * 256;          // 0..4095
    int bid = bs * 2 + oh;
    s += part2[(bid * 64 + ol) * 2 + 0];
    ss += part2[(bid * 64 + ol) * 2 + 1];
  }
  rs[tid] = s;
  rss[tid] = ss;
  __syncthreads();
  for (int st = 128; st > 0; st >>= 1) {
    if (tid < st) {
      rs[tid] += rs[tid + st];
      rss[tid] += rss[tid + st];
    }
    __syncthreads();
  }
  if (tid == 0) {
    const float N = 65536.f;
    float mean = rs[0] / N;
    float var = rss[0] / N - mean * mean;
    float scale = g[o] * rsqrtf(var + EPS_);
    sc[o] = scale;
    sh[o] = bt[o] - mean * scale;
  }
}

// ---------------- normalize + transpose to seq[b][t][c] (f16) ----------------
__global__ __launch_bounds__(256, 4) void k_norm(const unsigned short* __restrict__ y2,
                                                 const float* __restrict__ sc,
                                                 const float* __restrict__ sh,
                                                 unsigned short* __restrict__ seq) {
  __shared__ unsigned short tile[128][34];
  const int tid = threadIdx.x;
  const int b = blockIdx.x >> 3, tt0 = (blockIdx.x & 7) * 32;
  {
    const int o = tid >> 1, th = tid & 1;
    const float scv = sc[o], shv = sh[o];
    const unsigned short* src = y2 + (b * 128 + o) * 256 + tt0 + th * 16;
#pragma unroll
    for (int j = 0; j < 16; j++) {
      float v = h2f(src[j]) * scv + shv;
      tile[o][th * 16 + j] = f2h(v);
    }
  }
  __syncthreads();
  {
    const int tl = tid >> 3, og = tid & 7;
    unsigned short* dst = seq + ((b * 256) + tt0 + tl) * 128 + og * 16;
#pragma unroll
    for (int j = 0; j < 16; j++) dst[j] = tile[og * 16 + j][tl];
  }
}

// ---------------- persistent 2-layer LSTM ----------------
// grid 256 = batchgroup(16) x unitgroup(16); block 256 = 4 waves (one gate each)
#define LDW0(kk) (*(const short8*)&w0f[(((wv)*12 + (kk)) * 64 + lane) * 8])
#define LDW1(kk) (*(const short8*)&w1f[(((wv)*16 + (kk)) * 64 + lane) * 8])

__global__ __launch_bounds__(256, 1) void k_lstm(
    const unsigned short* __restrict__ seq, const float* __restrict__ wi0,
    const float* __restrict__ bi0, const float* __restrict__ wh0,
    const float* __restrict__ bh0, const float* __restrict__ wi1,
    const float* __restrict__ bi1, const float* __restrict__ wh1,
    const float* __restrict__ bh1, unsigned short* __restrict__ h0buf,
    unsigned short* __restrict__ h1buf, int* __restrict__ flags,
    float* __restrict__ hfinal) {
  __shared__ unsigned short w0f[4 * 12 * 64 * 8];  // 49152 B
  __shared__ unsigned short w1f[4 * 16 * 64 * 8];  // 65536 B
  __shared__ unsigned short hs0[16 * 264];         // 8448 B (padded rows)
  __shared__ unsigned short hs1[16 * 264];
  __shared__ float gx[4][16][16];                  // 4096 B

  const int tid = threadIdx.x;
  const int gb = blockIdx.x >> 4, gh = blockIdx.x & 15;
  const int b0 = gb * 16, u0 = gh * 16;
  const int wv = tid >> 6, lane = tid & 63;
  const int ar = lane & 15;            // A-frag row / D col
  const int ac8 = (lane >> 4) * 8;     // A-frag k sub-offset
  const int cr = tid >> 4, cc = tid & 15;  // cell-update (row,col)
  const int hrow = (b0 + cr) * 256 + u0 + cc;

  // --- stage weights into MFMA B-fragment layout (f16) ---
  for (int n = tid; n < 4 * 384 * 16; n += 256) {
    int w = n / (384 * 16);
    int r = n - w * (384 * 16);
    int k = r >> 4, c = r & 15;
    int col = w * 256 + u0 + c;
    float v = (k < 128) ? wi0[k * 1024 + col] : wh0[(k - 128) * 1024 + col];
    int kk = k >> 5, l = (((k >> 3) & 3) << 4) | c, e = k & 7;
    w0f[((w * 12 + kk) * 64 + l) * 8 + e] = f2h(v);
  }
  for (int n = tid; n < 4 * 512 * 16; n += 256) {
    int w = n / (512 * 16);
    int r = n - w * (512 * 16);
    int k = r >> 4, c = r & 15;
    int col = w * 256 + u0 + c;
    float v = (k < 256) ? wi1[k * 1024 + col] : wh1[(k - 256) * 1024 + col];
    int kk = k >> 5, l = (((k >> 3) & 3) << 4) | c, e = k & 7;
    w1f[((w * 16 + kk) * 64 + l) * 8 + e] = f2h(v);
  }
  const int gcol = wv * 256 + u0 + ar;
  const float b0v = bi0[gcol] + bh0[gcol];
  const float b1v = bi1[gcol] + bh1[gcol];
  float c0 = 0.f, c1 = 0.f, h1v = 0.f;
  __syncthreads();

  // --- prologue: h0(0) = cell(x(0), h=0, c=0) ---
  {
    const unsigned short* xp = seq + ((b0 + ar) * 256 + 0) * 128 + ac8;
    short8 xa0 = *(const short8*)(xp + 0);
    short8 xa1 = *(const short8*)(xp + 32);
    short8 xa2 = *(const short8*)(xp + 64);
    short8 xa3 = *(const short8*)(xp + 96);
    f32x4 acc = {b0v, b0v, b0v, b0v};
    acc = __builtin_amdgcn_mfma_f32_16x16x32_f16(xa0, LDW0(0), acc, 0, 0, 0);
    acc = __builtin_amdgcn_mfma_f32_16x16x32_f16(xa1, LDW0(1), acc, 0, 0, 0);
    acc = __builtin_amdgcn_mfma_f32_16x16x32_f16(xa2, LDW0(2), acc, 0, 0, 0);
    acc = __builtin_amdgcn_mfma_f32_16x16x32_f16(xa3, LDW0(3), acc, 0, 0, 0);
#pragma unroll
    for (int r = 0; r < 4; r++) gx[wv][(lane >> 4) * 4 + r][ar] = acc[r];
    __syncthreads();
    float gi = gx[0][cr][cc], gfv = gx[1][cr][cc], gg = gx[2][cr][cc],
          go = gx[3][cr][cc];
    c0 = sigf(gfv) * c0 + sigf(gi) * tanhfast(gg);
    float h0v = sigf(go) * tanhfast(c0);
    __hip_atomic_store(h0buf + hrow, f2h(h0v), __ATOMIC_RELAXED,
                       __HIP_MEMORY_SCOPE_AGENT);
    __syncthreads();  // drains vmcnt: stores complete before flag
    if (tid == 0) {
      __hip_atomic_store(&flags[blockIdx.x], 1, __ATOMIC_RELAXED,
                         __HIP_MEMORY_SCOPE_AGENT);
      int* gf = flags + gb * 16;
      for (;;) {
        int mn = 0x7fffffff;
#pragma unroll
        for (int j = 0; j < 16; j++)
          mn = min(mn, __hip_atomic_load(&gf[j], __ATOMIC_RELAXED,
                                         __HIP_MEMORY_SCOPE_AGENT));
        if (mn >= 1) break;
        __builtin_amdgcn_s_sleep(2);
      }
    }
    __syncthreads();
  }

  // --- main loop: interval t computes layer1(t) then layer0(t+1) ---
  for (int t = 0; t < 256; t++) {
    const unsigned short* src0 = h0buf + (t & 1) * 65536;         // h0(t)
    const unsigned short* src1 = h1buf + ((t + 1) & 1) * 65536;   // h1(t-1)
    for (int u = tid; u < 1024; u += 256) {
      int r = u >> 6, cg = u & 63;
      u64 v0 = __hip_atomic_load((const u64*)(src0 + (b0 + r) * 256 + cg * 4),
                                 __ATOMIC_RELAXED, __HIP_MEMORY_SCOPE_AGENT);
      u64 v1 = __hip_atomic_load((const u64*)(src1 + (b0 + r) * 256 + cg * 4),
                                 __ATOMIC_RELAXED, __HIP_MEMORY_SCOPE_AGENT);
      *(u64*)&hs0[r * 264 + cg * 4] = v0;
      *(u64*)&hs1[r * 264 + cg * 4] = v1;
    }
    short8 xa0, xa1, xa2, xa3;
    if (t < 255) {
      const unsigned short* xp = seq + ((b0 + ar) * 256 + (t + 1)) * 128 + ac8;
      xa0 = *(const short8*)(xp + 0);
      xa1 = *(const short8*)(xp + 32);
      xa2 = *(const short8*)(xp + 64);
      xa3 = *(const short8*)(xp + 96);
    }
    __syncthreads();
    short8 a[16];
#pragma unroll
    for (int kk = 0; kk < 8; kk++)
      a[kk] = *(const short8*)&hs0[ar * 264 + kk * 32 + ac8];
#pragma unroll
    for (int kk = 0; kk < 8; kk++)
      a[8 + kk] = *(const short8*)&hs1[ar * 264 + kk * 32 + ac8];
    // layer1 gates: [h0(t) | h1(t-1)] @ [wi1; wh1] + b
    f32x4 acc1a = {b1v, b1v, b1v, b1v};
    f32x4 acc1b = {0.f, 0.f, 0.f, 0.f};
#pragma unroll
    for (int kk = 0; kk < 8; kk++) {
      acc1a = __builtin_amdgcn_mfma_f32_16x16x32_f16(a[kk], LDW1(kk), acc1a, 0, 0, 0);
      acc1b = __builtin_amdgcn_mfma_f32_16x16x32_f16(a[kk + 8], LDW1(kk + 8), acc1b, 0, 0, 0);
    }
#pragma unroll
    for (int r = 0; r < 4; r++)
      gx[wv][(lane >> 4) * 4 + r][ar] = acc1a[r] + acc1b[r];
    __syncthreads();
    {
      float gi = gx[0][cr][cc], gfv = gx[1][cr][cc], gg = gx[2][cr][cc],
            go = gx[3][cr][cc];
      c1 = sigf(gfv) * c1 + sigf(gi) * tanhfast(gg);
      h1v = sigf(go) * tanhfast(c1);
      __hip_atomic_store(h1buf + (t & 1) * 65536 + hrow, f2h(h1v),
                         __ATOMIC_RELAXED, __HIP_MEMORY_SCOPE_AGENT);
    }
    __syncthreads();  // gx reuse
    if (t < 255) {
      // layer0 gates for t+1: [x(t+1) | h0(t)] @ [wi0; wh0] + b
      f32x4 acc0a = {b0v, b0v, b0v, b0v};
      f32x4 acc0b = {0.f, 0.f, 0.f, 0.f};
      acc0a = __builtin_amdgcn_mfma_f32_16x16x32_f16(xa0, LDW0(0), acc0a, 0, 0, 0);
      acc0b = __builtin_amdgcn_mfma_f32_16x16x32_f16(xa1, LDW0(1), acc0b, 0, 0, 0);
      acc0a = __builtin_amdgcn_mfma_f32_16x16x32_f16(xa2, LDW0(2), acc0a, 0, 0, 0);
      acc0b = __builtin_amdgcn_mfma_f32_16x16x32_f16(xa3, LDW0(3), acc0b, 0, 0, 0);
#pragma unroll
      for (int kk = 0; kk < 8; kk += 2) {
        acc0a = __builtin_amdgcn_mfma_f32_16x16x32_f16(a[kk], LDW0(4 + kk), acc0a, 0, 0, 0);
        acc0b = __builtin_amdgcn_mfma_f32_16x16x32_f16(a[kk + 1], LDW0(5 + kk), acc0b, 0, 0, 0);
      }
#pragma unroll
      for (int r = 0; r < 4; r++)
        gx[wv][(lane >> 4) * 4 + r][ar] = acc0a[r] + acc0b[r];
      __syncthreads();
      float gi = gx[0][cr][cc], gfv = gx[1][cr][cc], gg = gx[2][cr][cc],
            go = gx[3][cr][cc];
      c0 = sigf(gfv) * c0 + sigf(gi) * tanhfast(gg);
      float h0v = sigf(go) * tanhfast(c0);
      __hip_atomic_store(h0buf + ((t + 1) & 1) * 65536 + hrow, f2h(h0v),
                         __ATOMIC_RELAXED, __HIP_MEMORY_SCOPE_AGENT);
    }
    __syncthreads();  // drains vmcnt before publish
    if (tid == 0) {
      __hip_atomic_store(&flags[blockIdx.x], t + 2, __ATOMIC_RELAXED,
                         __HIP_MEMORY_SCOPE_AGENT);
      int* gf = flags + gb * 16;
      for (;;) {
        int mn = 0x7fffffff;
#pragma unroll
        for (int j = 0; j < 16; j++)
          mn = min(mn, __hip_atomic_load(&gf[j], __ATOMIC_RELAXED,
                                         __HIP_MEMORY_SCOPE_AGENT));
        if (mn >= t + 2) break;
        __builtin_amdgcn_s_sleep(2);
      }
    }
    __syncthreads();
  }
  hfinal[hrow] = h1v;  // plain store; next kernel sees it (kernel boundary)
}

// ---------------- MLP head ----------------
__global__ __launch_bounds__(256, 2) void k_mlp(const float* __restrict__ hfinal,
                                                const float* __restrict__ s,
                                                const float* __restrict__ w1,
                                                const float* __restrict__ b1,
                                                const float* __restrict__ w2,
                                                const float* __restrict__ b2,
                                                const float* __restrict__ wp,
                                                const float* __restrict__ bp,
                                                float* __restrict__ out) {
  __shared__ float feat[257];
  __shared__ float z1[256];
  __shared__ float z2[128];
  const int tid = threadIdx.x, b = blockIdx.x;
  feat[tid] = hfinal[b * 256 + tid];
  if (tid == 0) feat[256] = s[b];
  __syncthreads();
  float a = b1[tid];
  for (int i = 0; i < 257; i++) a += feat[i] * w1[i * 256 + tid];
  z1[tid] = fmaxf(a, 0.f);
  __syncthreads();
  if (tid < 128) {
    float a2 = b2[tid];
    for (int i = 0; i < 256; i++) a2 += z1[i] * w2[i * 128 + tid];
    z2[tid] = fmaxf(a2, 0.f);
  }
  __syncthreads();
  if (tid == 0) {
    float sv = bp[0];
    for (int i = 0; i < 128; i++) sv += z2[i] * wp[i];
    out[b] = fmaxf(sv, 0.f) + log1pf(__expf(-fabsf(sv)));  // softplus, stable
  }
}

extern "C" void kernel_launch(void* const* d_in, const int* in_sizes, int n_in,
                              void* d_out, int out_size, void* d_ws, size_t ws_size,
                              hipStream_t stream) {
  const float* x = (const float*)d_in[0];
  const float* s = (const float*)d_in[1];
  const float* c1w = (const float*)d_in[2];
  const float* c1b = (const float*)d_in[3];
  const float* bn1g = (const float*)d_in[4];
  const float* bn1b = (const float*)d_in[5];
  const float* c2w = (const float*)d_in[6];
  const float* c2b = (const float*)d_in[7];
  const float* bn2g = (const float*)d_in[8];
  const float* bn2b = (const float*)d_in[9];
  const float* wi0 = (const float*)d_in[10];
  const float* bi0 = (const float*)d_in[11];
  const float* wh0 = (const float*)d_in[12];
  const float* bh0 = (const float*)d_in[13];
  const float* wi1 = (const float*)d_in[14];
  const float* bi1 = (const float*)d_in[15];
  const float* wh1 = (const float*)d_in[16];
  const float* bh1 = (const float*)d_in[17];
  const float* w1 = (const float*)d_in[18];
  const float* b1 = (const float*)d_in[19];
  const float* w2 = (const float*)d_in[20];
  const float* b2 = (const float*)d_in[21];
  const float* wp = (const float*)d_in[22];
  const float* bp = (const float*)d_in[23];

  char* ws = (char*)d_ws;
  int* flags = (int*)(ws + OFF_FLAGS);
  float* sc1 = (float*)(ws + OFF_SC1);
  float* sh1 = (float*)(ws + OFF_SH1);
  float* sc2 = (float*)(ws + OFF_SC2);
  float* sh2 = (float*)(ws + OFF_SH2);
  float* part1 = (float*)(ws + OFF_PART1);
  float* part2 = (float*)(ws + OFF_PART2);
  unsigned short* y2 = (unsigned short*)(ws + OFF_Y2);
  unsigned short* seq = (unsigned short*)(ws + OFF_SEQ);
  unsigned short* h0b = (unsigned short*)(ws + OFF_H0);
  unsigned short* h1b = (unsigned short*)(ws + OFF_H1);
  float* hf = (float*)(ws + OFF_HF);

  k_init<<<64, 256, 0, stream>>>(flags, (u64*)(ws + OFF_H0));
  k_conv1<<<256, 256, 0, stream>>>(x, c1w, c1b, part1);
  k_bn1<<<64, 256, 0, stream>>>(part1, bn1g, bn1b, sc1, sh1);
  k_conv2<<<8192, 256, 0, stream>>>(x, c1w, c1b, sc1, sh1, c2w, c2b, y2, part2);
  k_bn2<<<128, 256, 0, stream>>>(part2, bn2g, bn2b, sc2, sh2);
  k_norm<<<2048, 256, 0, stream>>>(y2, sc2, sh2, seq);
  k_lstm<<<256, 256, 0, stream>>>(seq, wi0, bi0, wh0, bh0, wi1, bi1, wh1, bh1,
                                  h0b, h1b, flags, hf);
  k_mlp<<<256, 256, 0, stream>>>(hf, s, w1, b1, w2, b2, wp, bp, (float*)d_out);
}

// Round 2
// 1508.294 us; speedup vs baseline: 1.1123x; 1.1123x over previous
//
#include <hip/hip_runtime.h>
#include <hip/hip_bf16.h>
#include <hip/hip_fp16.h>
#include <math.h>

#define B_ 256
#define C1_ 64
#define C2_ 128
#define T_ 256
#define H_ 256
#define EPS_ 1e-5f

typedef short short8 __attribute__((ext_vector_type(8)));
typedef float f32x4 __attribute__((ext_vector_type(4)));
typedef unsigned long long u64;

// ---------------- ws layout (bytes) ----------------
#define OFF_CNT   0               // 16 groups * 260 ints = 16640 B
#define OFF_SC1   16640           // 64 f32
#define OFF_SH1   (16640 + 256)
#define OFF_SC2   (16640 + 512)   // 128 f32
#define OFF_SH2   (16640 + 1024)
#define OFF_PART1 18432           // 256*64*2*4   = 131072
#define OFF_PART2 149504          // 8192*64*2*4  = 4194304
#define OFF_SEQ   4343808         // 256*256*128*2 = 16777216 (f16, [b][t][c])
#define OFF_H0    21121024        // 2*256*256*2 = 262144 (f16 ping-pong)
#define OFF_H1    21383168        // 262144
#define OFF_HF    21645312        // 256*256*4 = 262144 (f32)
// end: 21907456 bytes (< round-1 footprint)

__device__ __forceinline__ unsigned short f2h(float f) {
  return __half_as_ushort(__float2half(f));
}
__device__ __forceinline__ float h2f(unsigned short u) {
  return __half2float(__ushort_as_half(u));
}
__device__ __forceinline__ float sigf(float x) { return 1.f / (1.f + __expf(-x)); }
__device__ __forceinline__ float tanhfast(float x) {
  return 1.f - 2.f / (__expf(2.f * x) + 1.f);
}

// pack 4 lanes' f16 into u64, lane with (lane&3)==0 stores
__device__ __forceinline__ void pack_store(unsigned short hu, unsigned short* dst,
                                           int lane) {
  unsigned int p0 = hu;
  unsigned int p1 = __shfl_down(p0, 1, 64);
  unsigned int p2 = __shfl_down(p0, 2, 64);
  unsigned int p3 = __shfl_down(p0, 3, 64);
  if ((lane & 3) == 0) {
    u64 pv = (u64)p0 | ((u64)p1 << 16) | ((u64)p2 << 32) | ((u64)p3 << 48);
    __hip_atomic_store((u64*)dst, pv, __ATOMIC_RELAXED, __HIP_MEMORY_SCOPE_AGENT);
  }
}

// ---------------- init: zero rendezvous counters ----------------
__global__ void k_init(u64* cnt) {
  int t = blockIdx.x * blockDim.x + threadIdx.x;
  if (t < 2080) cnt[t] = 0ULL;
}

// ---------------- conv1 + relu + pool4, BN1 partial stats ----------------
__global__ __launch_bounds__(256, 2) void k_conv1(const float* __restrict__ x,
                                                  const float* __restrict__ w1,
                                                  const float* __restrict__ b1,
                                                  float* __restrict__ part1) {
  __shared__ float xs[4104];
  __shared__ float w1s[576];
  __shared__ float b1s[64];
  __shared__ float red[64][4][2];
  const int tid = threadIdx.x, b = blockIdx.x;
  for (int j = tid; j < 4104; j += 256) {
    int p = j - 4;
    xs[j] = (p >= 0 && p < 4096) ? x[b * 4096 + p] : 0.f;
  }
  for (int j = tid; j < 576; j += 256) w1s[j] = w1[j];
  if (tid < 64) b1s[tid] = b1[tid];
  __syncthreads();
  const int c = tid >> 2, lq = tid & 3;
  float wr[9];
#pragma unroll
  for (int k = 0; k < 9; k++) wr[k] = w1s[c * 9 + k];
  const float bb = b1s[c];
  float S = 0.f, SS = 0.f;
  for (int li = 0; li < 256; li++) {
    int l = lq * 256 + li;
    int base = 4 * l;
    float a4 = 0.f;
#pragma unroll
    for (int jj = 0; jj < 4; jj++) {
      float cv = bb;
#pragma unroll
      for (int k = 0; k < 9; k++) cv += xs[base + jj + k] * wr[k];
      a4 += fmaxf(cv, 0.f);
    }
    float y = 0.25f * a4;
    S += y;
    SS += y * y;
  }
  red[c][lq][0] = S;
  red[c][lq][1] = SS;
  __syncthreads();
  if (tid < 64) {
    float s = 0.f, ss = 0.f;
#pragma unroll
    for (int q = 0; q < 4; q++) {
      s += red[tid][q][0];
      ss += red[tid][q][1];
    }
    part1[(b * 64 + tid) * 2 + 0] = s;
    part1[(b * 64 + tid) * 2 + 1] = ss;
  }
}

// ---------------- BN1 finalize ----------------
__global__ void k_bn1(const float* __restrict__ part1, const float* __restrict__ g,
                      const float* __restrict__ bt, float* __restrict__ sc,
                      float* __restrict__ sh) {
  __shared__ float rs[256], rss[256];
  const int c = blockIdx.x, tid = threadIdx.x;
  rs[tid] = part1[(tid * 64 + c) * 2 + 0];
  rss[tid] = part1[(tid * 64 + c) * 2 + 1];
  __syncthreads();
  for (int st = 128; st > 0; st >>= 1) {
    if (tid < st) {
      rs[tid] += rs[tid + st];
      rss[tid] += rss[tid + st];
    }
    __syncthreads();
  }
  if (tid == 0) {
    const float N = 256.f * 1024.f;
    float mean = rs[0] / N;
    float var = rss[0] / N - mean * mean;
    float scale = g[c] * rsqrtf(var + EPS_);
    sc[c] = scale;
    sh[c] = bt[c] - mean * scale;
  }
}

// ---------------- conv2 (recomputes conv1+bn1 on the fly) ----------------
// grid: b(256) x slice(16) x ohalf(2) = 8192 blocks
// writes pooled raw y2 directly in seq layout [b][t][c] (f16, pre-BN2)
__global__ __launch_bounds__(256, 2) void k_conv2(
    const float* __restrict__ x, const float* __restrict__ w1,
    const float* __restrict__ b1, const float* __restrict__ sc1,
    const float* __restrict__ sh1, const float* __restrict__ w2,
    const float* __restrict__ b2, unsigned short* __restrict__ seq,
    float* __restrict__ part2) {
  __shared__ float xs[288];
  __shared__ float y1n[64][68];
  __shared__ unsigned short w2s[64 * 5 * 64];
  __shared__ float w1s[576], b1s[64], s1s[64], h1s[64], b2s[64];
  __shared__ float red[64][4][2];
  const int tid = threadIdx.x;
  const int bid = blockIdx.x;
  const int oh = bid & 1, slice = (bid >> 1) & 15, b = bid >> 5;
  const int l0 = slice * 64;
  for (int j = tid; j < 288; j += 256) {
    int p = 4 * l0 - 12 + j;
    xs[j] = (p >= 0 && p < 4096) ? x[b * 4096 + p] : 0.f;
  }
  for (int j = tid; j < 576; j += 256) w1s[j] = w1[j];
  if (tid < 64) {
    b1s[tid] = b1[tid];
    s1s[tid] = sc1[tid];
    h1s[tid] = sh1[tid];
    b2s[tid] = b2[oh * 64 + tid];
  }
  for (int j = tid; j < 64 * 5 * 64; j += 256) {
    int ol = j & 63, ik = j >> 6;
    int i = ik / 5, k = ik - i * 5;
    w2s[j] = f2h(w2[(oh * 64 + ol) * 320 + i * 5 + k]);
  }
  __syncthreads();
  for (int j = tid; j < 64 * 68; j += 256) {
    int lw = j % 68, i = j / 68;
    int l = l0 - 2 + lw;
    float v = 0.f;
    if (l >= 0 && l < 1024) {
      float a4 = 0.f;
#pragma unroll
      for (int jj = 0; jj < 4; jj++) {
        float cv = b1s[i];
#pragma unroll
        for (int k = 0; k < 9; k++) cv += xs[4 * lw + jj + k] * w1s[i * 9 + k];
        a4 += fmaxf(cv, 0.f);
      }
      v = 0.25f * a4 * s1s[i] + h1s[i];
    }
    y1n[i][lw] = v;
  }
  __syncthreads();
  const int ol = tid & 63, lh = tid >> 6;
  float acc[16];
#pragma unroll
  for (int u = 0; u < 16; u++) acc[u] = 0.f;
  for (int i = 0; i < 64; i++) {
    float xr[20];
#pragma unroll
    for (int q = 0; q < 5; q++) {
      float4 tv = *(const float4*)&y1n[i][lh * 16 + q * 4];
      xr[q * 4 + 0] = tv.x;
      xr[q * 4 + 1] = tv.y;
      xr[q * 4 + 2] = tv.z;
      xr[q * 4 + 3] = tv.w;
    }
#pragma unroll
    for (int k = 0; k < 5; k++) {
      float wv = h2f(w2s[(i * 5 + k) * 64 + ol]);
#pragma unroll
      for (int u = 0; u < 16; u++) acc[u] += xr[u + k] * wv;
    }
  }
  const float b2v = b2s[ol];
  float yo[4];
  float S = 0.f, SS = 0.f;
#pragma unroll
  for (int tt = 0; tt < 4; tt++) {
    float sum = 0.f;
#pragma unroll
    for (int j = 0; j < 4; j++) sum += fmaxf(acc[tt * 4 + j] + b2v, 0.f);
    yo[tt] = 0.25f * sum;
    S += yo[tt];
    SS += yo[tt] * yo[tt];
  }
  {
    const int o = oh * 64 + ol;
    const int t0 = slice * 16 + lh * 4;
#pragma unroll
    for (int tt = 0; tt < 4; tt++)
      seq[(b * 256 + t0 + tt) * 128 + o] = f2h(yo[tt]);
  }
  red[ol][lh][0] = S;
  red[ol][lh][1] = SS;
  __syncthreads();
  if (tid < 64) {
    float s = 0.f, ss = 0.f;
#pragma unroll
    for (int q = 0; q < 4; q++) {
      s += red[tid][q][0];
      ss += red[tid][q][1];
    }
    part2[(bid * 64 + tid) * 2 + 0] = s;
    part2[(bid * 64 + tid) * 2 + 1] = ss;
  }
}

// ---------------- BN2 finalize ----------------
__global__ void k_bn2(const float* __restrict__ part2, const float* __restrict__ g,
                      const float* __restrict__ bt, float* __restrict__ sc,
                      float* __restrict__ sh) {
  __shared__ float rs[256], rss[256];
  const int o = blockIdx.x, tid = threadIdx.x;
  const int oh = o >> 6, ol = o & 63;
  float s = 0.f, ss = 0.f;
  for (int q = 0; q < 16; q++) {
    int bs = tid + q * 256;
    int bid = bs * 2 + oh;
    s += part2[(bid * 64 + ol) * 2 + 0];
    ss += part2[(bid * 64 + ol) * 2 + 1];
  }
  rs[tid] = s;
  rss[tid] = ss;
  __syncthreads();
  for (int st = 128; st > 0; st >>= 1) {
    if (tid < st) {
      rs[tid] += rs[tid + st];
      rss[tid] += rss[tid + st];
    }
    __syncthreads();
  }
  if (tid == 0) {
    const float N = 65536.f;
    float mean = rs[0] / N;
    float var = rss[0] / N - mean * mean;
    float scale = g[o] * rsqrtf(var + EPS_);
    sc[o] = scale;
    sh[o] = bt[o] - mean * scale;
  }
}

// ---------------- BN2 apply in-place on seq (f16) ----------------
__global__ __launch_bounds__(256, 4) void k_norm2(u64* __restrict__ seq64,
                                                  const float* __restrict__ sc,
                                                  const float* __restrict__ sh) {
  __shared__ float scs[128], shs[128];
  const int tid = threadIdx.x;
  if (tid < 128) {
    scs[tid] = sc[tid];
    shs[tid] = sh[tid];
  }
  __syncthreads();
#pragma unroll
  for (int j = 0; j < 4; j++) {
    int i = (blockIdx.x * 256 + tid) + j * 524288;
    u64 v = seq64[i];
    int o0 = (i * 4) & 127;
    u64 r = 0;
#pragma unroll
    for (int k = 0; k < 4; k++) {
      float f = h2f((unsigned short)(v >> (16 * k)));
      f = f * scs[o0 + k] + shs[o0 + k];
      r |= (u64)f2h(f) << (16 * k);
    }
    seq64[i] = r;
  }
}

// ---------------- persistent 2-layer LSTM ----------------
// grid 256 = batchgroup(16) x unitgroup(16); block 256 = 4 waves (one gate each)
#define LDW0(kk) (*(const short8*)&w0f[(((wv)*12 + (kk)) * 64 + lane) * 8])
#define LDW1(kk) (*(const short8*)&w1f[(((wv)*16 + (kk)) * 64 + lane) * 8])

__global__ __launch_bounds__(256, 1) void k_lstm(
    const unsigned short* __restrict__ seq, const float* __restrict__ wi0,
    const float* __restrict__ bi0, const float* __restrict__ wh0,
    const float* __restrict__ bh0, const float* __restrict__ wi1,
    const float* __restrict__ bi1, const float* __restrict__ wh1,
    const float* __restrict__ bh1, unsigned short* __restrict__ h0buf,
    unsigned short* __restrict__ h1buf, int* __restrict__ cnt,
    float* __restrict__ hfinal) {
  __shared__ unsigned short w0f[4 * 12 * 64 * 8];  // 49152 B
  __shared__ unsigned short w1f[4 * 16 * 64 * 8];  // 65536 B
  __shared__ unsigned short hs0[16 * 264];         // 8448 B
  __shared__ unsigned short hs1[16 * 264];
  __shared__ float gx[2][4][16][16];               // 8192 B

  const int tid = threadIdx.x;
  const int gb = blockIdx.x >> 4, gh = blockIdx.x & 15;
  const int b0 = gb * 16, u0 = gh * 16;
  const int wv = tid >> 6, lane = tid & 63;
  const int ar = lane & 15;
  const int ac8 = (lane >> 4) * 8;
  const int cr = tid >> 4, cc = tid & 15;
  const int hrow = (b0 + cr) * 256 + u0 + cc;
  int* gcnt = cnt + gb * 260;

  // --- stage weights into MFMA B-fragment layout (f16) ---
  for (int n = tid; n < 4 * 384 * 16; n += 256) {
    int w = n / (384 * 16);
    int r = n - w * (384 * 16);
    int k = r >> 4, c = r & 15;
    int col = w * 256 + u0 + c;
    float v = (k < 128) ? wi0[k * 1024 + col] : wh0[(k - 128) * 1024 + col];
    int kk = k >> 5, l = (((k >> 3) & 3) << 4) | c, e = k & 7;
    w0f[((w * 12 + kk) * 64 + l) * 8 + e] = f2h(v);
  }
  for (int n = tid; n < 4 * 512 * 16; n += 256) {
    int w = n / (512 * 16);
    int r = n - w * (512 * 16);
    int k = r >> 4, c = r & 15;
    int col = w * 256 + u0 + c;
    float v = (k < 256) ? wi1[k * 1024 + col] : wh1[(k - 256) * 1024 + col];
    int kk = k >> 5, l = (((k >> 3) & 3) << 4) | c, e = k & 7;
    w1f[((w * 16 + kk) * 64 + l) * 8 + e] = f2h(v);
  }
  const int gcol = wv * 256 + u0 + ar;
  const float b0v = bi0[gcol] + bh0[gcol];
  const float b1v = bi1[gcol] + bh1[gcol];
  float c0 = 0.f, c1 = 0.f, h1v = 0.f;
  __syncthreads();

  // --- prologue: h0(0) = cell(x(0), h=0, c=0) ---
  {
    const unsigned short* xp = seq + ((b0 + ar) * 256 + 0) * 128 + ac8;
    short8 xa0 = *(const short8*)(xp + 0);
    short8 xa1 = *(const short8*)(xp + 32);
    short8 xa2 = *(const short8*)(xp + 64);
    short8 xa3 = *(const short8*)(xp + 96);
    f32x4 acc = {b0v, b0v, b0v, b0v};
    acc = __builtin_amdgcn_mfma_f32_16x16x32_f16(xa0, LDW0(0), acc, 0, 0, 0);
    acc = __builtin_amdgcn_mfma_f32_16x16x32_f16(xa1, LDW0(1), acc, 0, 0, 0);
    acc = __builtin_amdgcn_mfma_f32_16x16x32_f16(xa2, LDW0(2), acc, 0, 0, 0);
    acc = __builtin_amdgcn_mfma_f32_16x16x32_f16(xa3, LDW0(3), acc, 0, 0, 0);
#pragma unroll
    for (int r = 0; r < 4; r++) gx[0][wv][(lane >> 4) * 4 + r][ar] = acc[r];
    __syncthreads();
    float gi = gx[0][0][cr][cc], gfv = gx[0][1][cr][cc], gg = gx[0][2][cr][cc],
          go = gx[0][3][cr][cc];
    c0 = sigf(gfv) * c0 + sigf(gi) * tanhfast(gg);
    float h0v = sigf(go) * tanhfast(c0);
    pack_store(f2h(h0v), h0buf + hrow, lane);
    __syncthreads();  // drains vmcnt: stores complete before publish
    if (tid == 0)
      __hip_atomic_fetch_add(&gcnt[0], 1, __ATOMIC_RELAXED, __HIP_MEMORY_SCOPE_AGENT);
  }

  // --- main loop: interval t computes layer1(t) then layer0(t+1) ---
  for (int t = 0; t < 256; t++) {
    // prefetch x(t+1) (independent of rendezvous)
    short8 xa0, xa1, xa2, xa3;
    if (t < 255) {
      const unsigned short* xp = seq + ((b0 + ar) * 256 + (t + 1)) * 128 + ac8;
      xa0 = *(const short8*)(xp + 0);
      xa1 = *(const short8*)(xp + 32);
      xa2 = *(const short8*)(xp + 64);
      xa3 = *(const short8*)(xp + 96);
    }
    // rendezvous: all threads poll one counter (per-wave broadcast load)
    while (__hip_atomic_load(&gcnt[t], __ATOMIC_RELAXED, __HIP_MEMORY_SCOPE_AGENT) < 16) {
    }
    // stage h0(t), h1(t-1) into LDS
    const unsigned short* src0 = h0buf + (t & 1) * 65536;
    if (t == 0) {
      for (int u = tid; u < 1024; u += 256) {
        int r = u >> 6, cg = u & 63;
        u64 v0 = __hip_atomic_load((const u64*)(src0 + (b0 + r) * 256 + cg * 4),
                                   __ATOMIC_RELAXED, __HIP_MEMORY_SCOPE_AGENT);
        *(u64*)&hs0[r * 264 + cg * 4] = v0;
        *(u64*)&hs1[r * 264 + cg * 4] = 0ULL;  // h1(-1) = 0
      }
    } else {
      const unsigned short* src1 = h1buf + ((t + 1) & 1) * 65536;
      for (int u = tid; u < 1024; u += 256) {
        int r = u >> 6, cg = u & 63;
        u64 v0 = __hip_atomic_load((const u64*)(src0 + (b0 + r) * 256 + cg * 4),
                                   __ATOMIC_RELAXED, __HIP_MEMORY_SCOPE_AGENT);
        u64 v1 = __hip_atomic_load((const u64*)(src1 + (b0 + r) * 256 + cg * 4),
                                   __ATOMIC_RELAXED, __HIP_MEMORY_SCOPE_AGENT);
        *(u64*)&hs0[r * 264 + cg * 4] = v0;
        *(u64*)&hs1[r * 264 + cg * 4] = v1;
      }
    }
    __syncthreads();  // S1: staging complete
    short8 a[16];
#pragma unroll
    for (int kk = 0; kk < 8; kk++)
      a[kk] = *(const short8*)&hs0[ar * 264 + kk * 32 + ac8];
#pragma unroll
    for (int kk = 0; kk < 8; kk++)
      a[8 + kk] = *(const short8*)&hs1[ar * 264 + kk * 32 + ac8];
    // layer1(t): [h0(t) | h1(t-1)] @ [wi1; wh1] + b
    f32x4 acc1a = {b1v, b1v, b1v, b1v};
    f32x4 acc1b = {0.f, 0.f, 0.f, 0.f};
#pragma unroll
    for (int kk = 0; kk < 8; kk++) {
      acc1a = __builtin_amdgcn_mfma_f32_16x16x32_f16(a[kk], LDW1(kk), acc1a, 0, 0, 0);
      acc1b = __builtin_amdgcn_mfma_f32_16x16x32_f16(a[kk + 8], LDW1(kk + 8), acc1b, 0, 0, 0);
    }
    // layer0(t+1): [x(t+1) | h0(t)] @ [wi0; wh0] + b
    f32x4 acc0a = {b0v, b0v, b0v, b0v};
    f32x4 acc0b = {0.f, 0.f, 0.f, 0.f};
    if (t < 255) {
      acc0a = __builtin_amdgcn_mfma_f32_16x16x32_f16(xa0, LDW0(0), acc0a, 0, 0, 0);
      acc0b = __builtin_amdgcn_mfma_f32_16x16x32_f16(xa1, LDW0(1), acc0b, 0, 0, 0);
      acc0a = __builtin_amdgcn_mfma_f32_16x16x32_f16(xa2, LDW0(2), acc0a, 0, 0, 0);
      acc0b = __builtin_amdgcn_mfma_f32_16x16x32_f16(xa3, LDW0(3), acc0b, 0, 0, 0);
#pragma unroll
      for (int kk = 0; kk < 8; kk += 2) {
        acc0a = __builtin_amdgcn_mfma_f32_16x16x32_f16(a[kk], LDW0(4 + kk), acc0a, 0, 0, 0);
        acc0b = __builtin_amdgcn_mfma_f32_16x16x32_f16(a[kk + 1], LDW0(5 + kk), acc0b, 0, 0, 0);
      }
    }
#pragma unroll
    for (int r = 0; r < 4; r++)
      gx[0][wv][(lane >> 4) * 4 + r][ar] = acc1a[r] + acc1b[r];
    if (t < 255) {
#pragma unroll
      for (int r = 0; r < 4; r++)
        gx[1][wv][(lane >> 4) * 4 + r][ar] = acc0a[r] + acc0b[r];
    }
    __syncthreads();  // S2: gates ready
    {
      float gi = gx[0][0][cr][cc], gfv = gx[0][1][cr][cc], gg = gx[0][2][cr][cc],
            go = gx[0][3][cr][cc];
      c1 = sigf(gfv) * c1 + sigf(gi) * tanhfast(gg);
      h1v = sigf(go) * tanhfast(c1);
      pack_store(f2h(h1v), h1buf + (t & 1) * 65536 + hrow, lane);
    }
    if (t < 255) {
      float gi = gx[1][0][cr][cc], gfv = gx[1][1][cr][cc], gg = gx[1][2][cr][cc],
            go = gx[1][3][cr][cc];
      c0 = sigf(gfv) * c0 + sigf(gi) * tanhfast(gg);
      float h0v = sigf(go) * tanhfast(c0);
      pack_store(f2h(h0v), h0buf + ((t + 1) & 1) * 65536 + hrow, lane);
    }
    __syncthreads();  // S3: drains vmcnt before publish
    if (tid == 0 && t < 255)
      __hip_atomic_fetch_add(&gcnt[t + 1], 1, __ATOMIC_RELAXED,
                             __HIP_MEMORY_SCOPE_AGENT);
  }
  hfinal[hrow] = h1v;
}

// ---------------- MLP head ----------------
__global__ __launch_bounds__(256, 2) void k_mlp(const float* __restrict__ hfinal,
                                                const float* __restrict__ s,
                                                const float* __restrict__ w1,
                                                const float* __restrict__ b1,
                                                const float* __restrict__ w2,
                                                const float* __restrict__ b2,
                                                const float* __restrict__ wp,
                                                const float* __restrict__ bp,
                                                float* __restrict__ out) {
  __shared__ float feat[257];
  __shared__ float z1[256];
  __shared__ float z2[128];
  const int tid = threadIdx.x, b = blockIdx.x;
  feat[tid] = hfinal[b * 256 + tid];
  if (tid == 0) feat[256] = s[b];
  __syncthreads();
  float a = b1[tid];
  for (int i = 0; i < 257; i++) a += feat[i] * w1[i * 256 + tid];
  z1[tid] = fmaxf(a, 0.f);
  __syncthreads();
  if (tid < 128) {
    float a2 = b2[tid];
    for (int i = 0; i < 256; i++) a2 += z1[i] * w2[i * 128 + tid];
    z2[tid] = fmaxf(a2, 0.f);
  }
  __syncthreads();
  if (tid == 0) {
    float sv = bp[0];
    for (int i = 0; i < 128; i++) sv += z2[i] * wp[i];
    out[b] = fmaxf(sv, 0.f) + log1pf(__expf(-fabsf(sv)));
  }
}

extern "C" void kernel_launch(void* const* d_in, const int* in_sizes, int n_in,
                              void* d_out, int out_size, void* d_ws, size_t ws_size,
                              hipStream_t stream) {
  const float* x = (const float*)d_in[0];
  const float* s = (const float*)d_in[1];
  const float* c1w = (const float*)d_in[2];
  const float* c1b = (const float*)d_in[3];
  const float* bn1g = (const float*)d_in[4];
  const float* bn1b = (const float*)d_in[5];
  const float* c2w = (const float*)d_in[6];
  const float* c2b = (const float*)d_in[7];
  const float* bn2g = (const float*)d_in[8];
  const float* bn2b = (const float*)d_in[9];
  const float* wi0 = (const float*)d_in[10];
  const float* bi0 = (const float*)d_in[11];
  const float* wh0 = (const float*)d_in[12];
  const float* bh0 = (const float*)d_in[13];
  const float* wi1 = (const float*)d_in[14];
  const float* bi1 = (const float*)d_in[15];
  const float* wh1 = (const float*)d_in[16];
  const float* bh1 = (const float*)d_in[17];
  const float* w1 = (const float*)d_in[18];
  const float* b1 = (const float*)d_in[19];
  const float* w2 = (const float*)d_in[20];
  const float* b2 = (const float*)d_in[21];
  const float* wp = (const float*)d_in[22];
  const float* bp = (const float*)d_in[23];

  char* ws = (char*)d_ws;
  int* cnt = (int*)(ws + OFF_CNT);
  float* sc1 = (float*)(ws + OFF_SC1);
  float* sh1 = (float*)(ws + OFF_SH1);
  float* sc2 = (float*)(ws + OFF_SC2);
  float* sh2 = (float*)(ws + OFF_SH2);
  float* part1 = (float*)(ws + OFF_PART1);
  float* part2 = (float*)(ws + OFF_PART2);
  unsigned short* seq = (unsigned short*)(ws + OFF_SEQ);
  unsigned short* h0b = (unsigned short*)(ws + OFF_H0);
  unsigned short* h1b = (unsigned short*)(ws + OFF_H1);
  float* hf = (float*)(ws + OFF_HF);

  k_init<<<16, 256, 0, stream>>>((u64*)cnt);
  k_conv1<<<256, 256, 0, stream>>>(x, c1w, c1b, part1);
  k_bn1<<<64, 256, 0, stream>>>(part1, bn1g, bn1b, sc1, sh1);
  k_conv2<<<8192, 256, 0, stream>>>(x, c1w, c1b, sc1, sh1, c2w, c2b, seq, part2);
  k_bn2<<<128, 256, 0, stream>>>(part2, bn2g, bn2b, sc2, sh2);
  k_norm2<<<2048, 256, 0, stream>>>((u64*)seq, sc2, sh2);
  k_lstm<<<256, 256, 0, stream>>>(seq, wi0, bi0, wh0, bh0, wi1, bi1, wh1, bh1,
                                  h0b, h1b, cnt, hf);
  k_mlp<<<256, 256, 0, stream>>>(hf, s, w1, b1, w2, b2, wp, bp, (float*)d_out);
}

// Round 4
// 1444.721 us; speedup vs baseline: 1.1612x; 1.0440x over previous
//
#include <hip/hip_runtime.h>
#include <hip/hip_bf16.h>
#include <hip/hip_fp16.h>
#include <math.h>

#define EPSV 1e-5f

typedef short short8 __attribute__((ext_vector_type(8)));
typedef float f32x4 __attribute__((ext_vector_type(4)));
typedef unsigned long long u64;

// ---------------- ws layout (bytes) ----------------
#define OFF_FLAGSA 0              // 16*16 ints = 1024
#define OFF_FLAGSB 1024           // 1024
#define OFF_SC1    2048           // 64 f32
#define OFF_SH1    2304
#define OFF_SC2    2560           // 128 f32
#define OFF_SH2    3072
#define OFF_PART1  8192           // 256*64*2*4   = 131072
#define OFF_PART2  139264         // 256*128*2*4  = 262144
#define OFF_W2F    401408         // 40960 f16    = 81920
#define OFF_SEQ    483328         // 256*256*128*2 = 16777216 (f16, [b][t][c])
#define OFF_H0     17260544       // 2*256*256*2 = 262144 (f16 ping-pong)
#define OFF_H1     17522688       // 262144
#define OFF_HF     17784832       // 256*256*4 = 262144 (f32)
// end 18,046,976

__device__ __forceinline__ unsigned short f2h(float f) {
  return __half_as_ushort(__float2half(f));
}
__device__ __forceinline__ float h2f(unsigned short u) {
  return __half2float(__ushort_as_half(u));
}
__device__ __forceinline__ float sigf(float x) { return 1.f / (1.f + __expf(-x)); }
__device__ __forceinline__ float tanhfast(float x) {
  return 1.f - 2.f / (__expf(2.f * x) + 1.f);
}

// pack 4 lanes' f16 into u64, lane with (lane&3)==0 stores
__device__ __forceinline__ void pack_store(unsigned short hu, unsigned short* dst,
                                           int lane) {
  unsigned int p0 = hu;
  unsigned int p1 = __shfl_down(p0, 1, 64);
  unsigned int p2 = __shfl_down(p0, 2, 64);
  unsigned int p3 = __shfl_down(p0, 3, 64);
  if ((lane & 3) == 0) {
    u64 pv = (u64)p0 | ((u64)p1 << 16) | ((u64)p2 << 32) | ((u64)p3 << 48);
    __hip_atomic_store((u64*)dst, pv, __ATOMIC_RELAXED, __HIP_MEMORY_SCOPE_AGENT);
  }
}

// ---------------- init: zero rendezvous flags ----------------
__global__ void k_init(u64* f) {
  int t = threadIdx.x;
  if (t < 256) f[t] = 0ULL;  // 2048 B
}

// ---------------- conv1 + relu + pool4, BN1 partial stats ----------------
__global__ __launch_bounds__(256, 2) void k_conv1(const float* __restrict__ x,
                                                  const float* __restrict__ w1,
                                                  const float* __restrict__ b1,
                                                  float* __restrict__ part1) {
  __shared__ float xs[4104];
  __shared__ float w1s[576];
  __shared__ float b1s[64];
  __shared__ float red[64][4][2];
  const int tid = threadIdx.x, b = blockIdx.x;
  for (int j = tid; j < 4104; j += 256) {
    int p = j - 4;
    xs[j] = (p >= 0 && p < 4096) ? x[b * 4096 + p] : 0.f;
  }
  for (int j = tid; j < 576; j += 256) w1s[j] = w1[j];
  if (tid < 64) b1s[tid] = b1[tid];
  __syncthreads();
  const int c = tid >> 2, lq = tid & 3;
  float wr[9];
#pragma unroll
  for (int k = 0; k < 9; k++) wr[k] = w1s[c * 9 + k];
  const float bb = b1s[c];
  float S = 0.f, SS = 0.f;
  for (int li = 0; li < 256; li++) {
    int l = lq * 256 + li;
    int base = 4 * l;
    float a4 = 0.f;
#pragma unroll
    for (int jj = 0; jj < 4; jj++) {
      float cv = bb;
#pragma unroll
      for (int k = 0; k < 9; k++) cv += xs[base + jj + k] * wr[k];
      a4 += fmaxf(cv, 0.f);
    }
    float y = 0.25f * a4;
    S += y;
    SS += y * y;
  }
  red[c][lq][0] = S;
  red[c][lq][1] = SS;
  __syncthreads();
  if (tid < 64) {
    float s = 0.f, ss = 0.f;
#pragma unroll
    for (int q = 0; q < 4; q++) {
      s += red[tid][q][0];
      ss += red[tid][q][1];
    }
    part1[(b * 64 + tid) * 2 + 0] = s;
    part1[(b * 64 + tid) * 2 + 1] = ss;
  }
}

// ---------------- BN1 finalize ----------------
__global__ void k_bn1(const float* __restrict__ part1, const float* __restrict__ g,
                      const float* __restrict__ bt, float* __restrict__ sc,
                      float* __restrict__ sh) {
  __shared__ float rs[256], rss[256];
  const int c = blockIdx.x, tid = threadIdx.x;
  rs[tid] = part1[(tid * 64 + c) * 2 + 0];
  rss[tid] = part1[(tid * 64 + c) * 2 + 1];
  __syncthreads();
  for (int st = 128; st > 0; st >>= 1) {
    if (tid < st) {
      rs[tid] += rs[tid + st];
      rss[tid] += rss[tid + st];
    }
    __syncthreads();
  }
  if (tid == 0) {
    const float N = 256.f * 1024.f;
    float mean = rs[0] / N;
    float var = rss[0] / N - mean * mean;
    float scale = g[c] * rsqrtf(var + EPSV);
    sc[c] = scale;
    sh[c] = bt[c] - mean * scale;
  }
}

// ---------------- w2 -> MFMA B-fragment layout (f16) ----------------
// w2f[((sc*8+ot)*64+lane)*8+e]: sc=s*2+c2 (shift s<5, i-chunk c2<2)
// B_s[i][o] = w2[o*320 + i*5 + s], o=ot*16+(lane&15), i=c2*32+(lane>>4)*8+e
__global__ void k_w2frag(const float* __restrict__ w2,
                         unsigned short* __restrict__ w2f) {
  int n = blockIdx.x * 256 + threadIdx.x;  // < 40960
  if (n >= 40960) return;
  int e = n & 7, lane = (n >> 3) & 63, ot = (n >> 9) & 7, sc = n >> 12;
  int s = sc >> 1, c2 = sc & 1;
  int o = ot * 16 + (lane & 15);
  int i = c2 * 32 + ((lane >> 4) << 3) + e;
  w2f[n] = f2h(w2[o * 320 + i * 5 + s]);
}

// ---------------- conv2 via MFMA (recomputes conv1+bn1 into LDS y1t) -------
// grid 256 (one block per batch b), 256 threads
__global__ __launch_bounds__(256, 1) void k_conv2(
    const float* __restrict__ x, const float* __restrict__ w1,
    const float* __restrict__ b1, const float* __restrict__ sc1,
    const float* __restrict__ sh1, const unsigned short* __restrict__ w2f,
    const float* __restrict__ b2, unsigned short* __restrict__ seq,
    float* __restrict__ part2) {
  __shared__ float xs[4104];
  __shared__ unsigned short y1t[1028][66];  // row = l+2, col = i
  __shared__ float w1s[576], b1s[64], s1s[64], h1s[64], b2s[128];
  __shared__ float red[4][2][128];
  const int tid = threadIdx.x, b = blockIdx.x;
  for (int j = tid; j < 4104; j += 256) {
    int p = j - 4;
    xs[j] = (p >= 0 && p < 4096) ? x[b * 4096 + p] : 0.f;
  }
  for (int j = tid; j < 576; j += 256) w1s[j] = w1[j];
  if (tid < 64) {
    b1s[tid] = b1[tid];
    s1s[tid] = sc1[tid];
    h1s[tid] = sh1[tid];
  }
  if (tid < 128) b2s[tid] = b2[tid];
  // zero pad rows (l = -2,-1,1024,1025)
  if (tid < 132) {
    int r4 = tid / 33, c4 = tid % 33;
    int row = (r4 < 2) ? r4 : (1024 + r4);
    ((unsigned int*)&y1t[row][0])[c4] = 0u;
  }
  __syncthreads();
  // ---- conv1 recompute + BN1 + f16 -> y1t (transposed) ----
  {
    const int i2 = tid & 31, lg = tid >> 5;
    const int ia = 2 * i2, ib = ia + 1;
    float wra[9], wrb[9];
#pragma unroll
    for (int k = 0; k < 9; k++) {
      wra[k] = w1s[ia * 9 + k];
      wrb[k] = w1s[ib * 9 + k];
    }
    const float bia = b1s[ia], bib = b1s[ib];
    const float sa = s1s[ia], sb = s1s[ib], ha = h1s[ia], hb = h1s[ib];
    for (int j = 0; j < 128; j++) {
      int l = lg * 128 + j;
      float xv[12];
#pragma unroll
      for (int m = 0; m < 12; m++) xv[m] = xs[4 * l + m];
      float aa = 0.f, ab = 0.f;
#pragma unroll
      for (int jj = 0; jj < 4; jj++) {
        float ca = bia, cb = bib;
#pragma unroll
        for (int k = 0; k < 9; k++) {
          float xx = xv[jj + k];
          ca += xx * wra[k];
          cb += xx * wrb[k];
        }
        aa += fmaxf(ca, 0.f);
        ab += fmaxf(cb, 0.f);
      }
      float va = 0.25f * aa * sa + ha;
      float vb = 0.25f * ab * sb + hb;
      unsigned int pk = (unsigned int)f2h(va) | ((unsigned int)f2h(vb) << 16);
      *(unsigned int*)&y1t[l + 2][ia] = pk;
    }
  }
  __syncthreads();
  // ---- GEMM: C[l][o] = sum_{s,i} y1t[l+s][i] * w2f_s[i][o] ----
  const int wv = tid >> 6, lane = tid & 63;
  const int colo = lane & 15, rq = lane >> 4;
  float Sa[2][4], SSa[2][4];
#pragma unroll
  for (int a = 0; a < 2; a++)
#pragma unroll
    for (int c = 0; c < 4; c++) {
      Sa[a][c] = 0.f;
      SSa[a][c] = 0.f;
    }
#pragma unroll
  for (int og = 0; og < 2; og++) {
    short8 bf[4][10];
#pragma unroll
    for (int ot = 0; ot < 4; ot++)
#pragma unroll
      for (int sc = 0; sc < 10; sc++)
        bf[ot][sc] = *(const short8*)(w2f + ((sc * 8 + og * 4 + ot) * 64 + lane) * 8);
    for (int ltw = 0; ltw < 16; ltw++) {
      int lt = wv * 16 + ltw;
      int lbase = lt * 16;
      short8 af[10];
#pragma unroll
      for (int s = 0; s < 5; s++)
#pragma unroll
        for (int c2 = 0; c2 < 2; c2++)
          af[s * 2 + c2] =
              *(const short8*)&y1t[lbase + colo + s][c2 * 32 + rq * 8];
#pragma unroll
      for (int ot = 0; ot < 4; ot++) {
        f32x4 acc = {0.f, 0.f, 0.f, 0.f};
#pragma unroll
        for (int sc = 0; sc < 10; sc++)
          acc = __builtin_amdgcn_mfma_f32_16x16x32_f16(af[sc], bf[ot][sc], acc, 0, 0, 0);
        int o = (og * 4 + ot) * 16 + colo;
        float bv = b2s[o];
        float s4 = fmaxf(acc[0] + bv, 0.f) + fmaxf(acc[1] + bv, 0.f) +
                   fmaxf(acc[2] + bv, 0.f) + fmaxf(acc[3] + bv, 0.f);
        float y = 0.25f * s4;
        int t_out = lt * 4 + rq;
        seq[(b * 256 + t_out) * 128 + o] = f2h(y);
        Sa[og][ot] += y;
        SSa[og][ot] += y * y;
      }
    }
  }
  // stats: sum over the 4 row-quads (lanes differing in bits 4-5)
#pragma unroll
  for (int og = 0; og < 2; og++)
#pragma unroll
    for (int ot = 0; ot < 4; ot++) {
      float sv = Sa[og][ot], ssv = SSa[og][ot];
      sv += __shfl_xor(sv, 16, 64);
      sv += __shfl_xor(sv, 32, 64);
      ssv += __shfl_xor(ssv, 16, 64);
      ssv += __shfl_xor(ssv, 32, 64);
      if (rq == 0) {
        int o = (og * 4 + ot) * 16 + colo;
        red[wv][0][o] = sv;
        red[wv][1][o] = ssv;
      }
    }
  __syncthreads();
  if (tid < 128) {
    float s = red[0][0][tid] + red[1][0][tid] + red[2][0][tid] + red[3][0][tid];
    float ss = red[0][1][tid] + red[1][1][tid] + red[2][1][tid] + red[3][1][tid];
    part2[(b * 128 + tid) * 2 + 0] = s;
    part2[(b * 128 + tid) * 2 + 1] = ss;
  }
}

// ---------------- BN2 finalize ----------------
__global__ void k_bn2(const float* __restrict__ part2, const float* __restrict__ g,
                      const float* __restrict__ bt, float* __restrict__ sc,
                      float* __restrict__ sh) {
  __shared__ float rs[256], rss[256];
  const int o = blockIdx.x, tid = threadIdx.x;
  rs[tid] = part2[(tid * 128 + o) * 2 + 0];
  rss[tid] = part2[(tid * 128 + o) * 2 + 1];
  __syncthreads();
  for (int st = 128; st > 0; st >>= 1) {
    if (tid < st) {
      rs[tid] += rs[tid + st];
      rss[tid] += rss[tid + st];
    }
    __syncthreads();
  }
  if (tid == 0) {
    const float N = 65536.f;
    float mean = rs[0] / N;
    float var = rss[0] / N - mean * mean;
    float scale = g[o] * rsqrtf(var + EPSV);
    sc[o] = scale;
    sh[o] = bt[o] - mean * scale;
  }
}

// ---------------- BN2 apply in-place on seq (f16) ----------------
__global__ __launch_bounds__(256, 4) void k_norm2(u64* __restrict__ seq64,
                                                  const float* __restrict__ sc,
                                                  const float* __restrict__ sh) {
  __shared__ float scs[128], shs[128];
  const int tid = threadIdx.x;
  if (tid < 128) {
    scs[tid] = sc[tid];
    shs[tid] = sh[tid];
  }
  __syncthreads();
#pragma unroll
  for (int j = 0; j < 4; j++) {
    int i = (blockIdx.x * 256 + tid) + j * 524288;
    u64 v = seq64[i];
    int o0 = (i * 4) & 127;
    u64 r = 0;
#pragma unroll
    for (int k = 0; k < 4; k++) {
      float f = h2f((unsigned short)(v >> (16 * k)));
      f = f * scs[o0 + k] + shs[o0 + k];
      r |= (u64)f2h(f) << (16 * k);
    }
    seq64[i] = r;
  }
}

// ---------------- persistent 2-layer LSTM ----------------
// grid 256 = batchgroup(16) x unitgroup(16); block 256 = 4 waves (one gate each)
#define LDW0(kk) (*(const short8*)&w0f[(((wv)*12 + (kk)) * 64 + lane) * 8])
#define LDW1(kk) (*(const short8*)&w1f[(((wv)*16 + (kk)) * 64 + lane) * 8])

__global__ __launch_bounds__(256, 1) void k_lstm(
    const unsigned short* __restrict__ seq, const float* __restrict__ wi0,
    const float* __restrict__ bi0, const float* __restrict__ wh0,
    const float* __restrict__ bh0, const float* __restrict__ wi1,
    const float* __restrict__ bi1, const float* __restrict__ wh1,
    const float* __restrict__ bh1, unsigned short* __restrict__ h0buf,
    unsigned short* __restrict__ h1buf, int* __restrict__ flagsA,
    int* __restrict__ flagsB, float* __restrict__ hfinal) {
  __shared__ unsigned short w0f[4 * 12 * 64 * 8];  // 49152 B
  __shared__ unsigned short w1f[4 * 16 * 64 * 8];  // 65536 B
  __shared__ unsigned short hs0[16 * 264];
  __shared__ unsigned short hs1[16 * 264];
  __shared__ float gx[2][4][16][16];

  const int tid = threadIdx.x;
  const int gb = blockIdx.x >> 4, gh = blockIdx.x & 15;
  const int b0 = gb * 16, u0 = gh * 16;
  const int wv = tid >> 6, lane = tid & 63;
  const int ar = lane & 15;
  const int ac8 = (lane >> 4) * 8;
  const int cr = tid >> 4, cc = tid & 15;
  const int hrow = (b0 + cr) * 256 + u0 + cc;

  // --- stage weights into MFMA B-fragment layout (f16) ---
  for (int n = tid; n < 4 * 384 * 16; n += 256) {
    int w = n / (384 * 16);
    int r = n - w * (384 * 16);
    int k = r >> 4, c = r & 15;
    int col = w * 256 + u0 + c;
    float v = (k < 128) ? wi0[k * 1024 + col] : wh0[(k - 128) * 1024 + col];
    int kk = k >> 5, l = (((k >> 3) & 3) << 4) | c, e = k & 7;
    w0f[((w * 12 + kk) * 64 + l) * 8 + e] = f2h(v);
  }
  for (int n = tid; n < 4 * 512 * 16; n += 256) {
    int w = n / (512 * 16);
    int r = n - w * (512 * 16);
    int k = r >> 4, c = r & 15;
    int col = w * 256 + u0 + c;
    float v = (k < 256) ? wi1[k * 1024 + col] : wh1[(k - 256) * 1024 + col];
    int kk = k >> 5, l = (((k >> 3) & 3) << 4) | c, e = k & 7;
    w1f[((w * 16 + kk) * 64 + l) * 8 + e] = f2h(v);
  }
  const int gcol = wv * 256 + u0 + ar;
  const float b0v = bi0[gcol] + bh0[gcol];
  const float b1v = bi1[gcol] + bh1[gcol];
  float c0 = 0.f, c1 = 0.f, h1v = 0.f;
  __syncthreads();

  // --- preload weight fragments into registers (1 wave/SIMD -> big budget) ---
  short8 rw0[12], rw1[16];
#pragma unroll
  for (int kk = 0; kk < 12; kk++) rw0[kk] = LDW0(kk);
#pragma unroll
  for (int kk = 0; kk < 16; kk++) rw1[kk] = LDW1(kk);

  // --- prologue: h0(0) = cell(x(0), h=0, c=0); publish flagB=1 ---
  {
    const unsigned short* xp = seq + ((b0 + ar) * 256 + 0) * 128 + ac8;
    short8 xa0 = *(const short8*)(xp + 0);
    short8 xa1 = *(const short8*)(xp + 32);
    short8 xa2 = *(const short8*)(xp + 64);
    short8 xa3 = *(const short8*)(xp + 96);
    f32x4 acc = {b0v, b0v, b0v, b0v};
    acc = __builtin_amdgcn_mfma_f32_16x16x32_f16(xa0, rw0[0], acc, 0, 0, 0);
    acc = __builtin_amdgcn_mfma_f32_16x16x32_f16(xa1, rw0[1], acc, 0, 0, 0);
    acc = __builtin_amdgcn_mfma_f32_16x16x32_f16(xa2, rw0[2], acc, 0, 0, 0);
    acc = __builtin_amdgcn_mfma_f32_16x16x32_f16(xa3, rw0[3], acc, 0, 0, 0);
#pragma unroll
    for (int r = 0; r < 4; r++) gx[0][wv][(lane >> 4) * 4 + r][ar] = acc[r];
    __syncthreads();
    float gi = gx[0][0][cr][cc], gfv = gx[0][1][cr][cc], gg = gx[0][2][cr][cc],
          go = gx[0][3][cr][cc];
    c0 = sigf(gfv) * c0 + sigf(gi) * tanhfast(gg);
    float h0v = sigf(go) * tanhfast(c0);
    pack_store(f2h(h0v), h0buf + hrow, lane);
    __syncthreads();  // drains all waves' stores
    if (tid == 0)
      __hip_atomic_store(&flagsB[gb * 16 + gh], 1, __ATOMIC_RELAXED,
                         __HIP_MEMORY_SCOPE_AGENT);
  }

  // --- main loop: interval t computes layer1(t) then layer0(t+1) ---
  for (int t = 0; t < 256; t++) {
    // prefetch x(t+1) (plain loads; seq is read-only input to this kernel)
    short8 xa0, xa1, xa2, xa3;
    if (t < 255) {
      const unsigned short* xp = seq + ((b0 + ar) * 256 + (t + 1)) * 128 + ac8;
      xa0 = *(const short8*)(xp + 0);
      xa1 = *(const short8*)(xp + 32);
      xa2 = *(const short8*)(xp + 64);
      xa3 = *(const short8*)(xp + 96);
    }
    // ---- phase A: wait h1(t-1), stage hs1 ----
    if (t == 0) {
      for (int u = tid; u < 1024; u += 256) {
        int r = u >> 6, cg = u & 63;
        *(u64*)&hs1[r * 264 + cg * 4] = 0ULL;
      }
    } else {
      {
        const int* fp = flagsA + gb * 16 + (lane & 15);
        int v;
        do {
          v = __hip_atomic_load(fp, __ATOMIC_RELAXED, __HIP_MEMORY_SCOPE_AGENT);
        } while (!__all(v >= t));
      }
      const unsigned short* src1 = h1buf + ((t + 1) & 1) * 65536;  // h1(t-1)
      for (int u = tid; u < 1024; u += 256) {
        int r = u >> 6, cg = u & 63;
        u64 v1 = __hip_atomic_load((const u64*)(src1 + (b0 + r) * 256 + cg * 4),
                                   __ATOMIC_RELAXED, __HIP_MEMORY_SCOPE_AGENT);
        *(u64*)&hs1[r * 264 + cg * 4] = v1;
      }
    }
    // ---- phase B: wait h0(t), stage hs0 ----
    {
      const int* fp = flagsB + gb * 16 + (lane & 15);
      int v;
      do {
        v = __hip_atomic_load(fp, __ATOMIC_RELAXED, __HIP_MEMORY_SCOPE_AGENT);
      } while (!__all(v >= t + 1));
    }
    {
      const unsigned short* src0 = h0buf + (t & 1) * 65536;  // h0(t)
      for (int u = tid; u < 1024; u += 256) {
        int r = u >> 6, cg = u & 63;
        u64 v0 = __hip_atomic_load((const u64*)(src0 + (b0 + r) * 256 + cg * 4),
                                   __ATOMIC_RELAXED, __HIP_MEMORY_SCOPE_AGENT);
        *(u64*)&hs0[r * 264 + cg * 4] = v0;
      }
    }
    __syncthreads();  // S1: staging complete
    short8 a[16];
#pragma unroll
    for (int kk = 0; kk < 8; kk++)
      a[kk] = *(const short8*)&hs0[ar * 264 + kk * 32 + ac8];
#pragma unroll
    for (int kk = 0; kk < 8; kk++)
      a[8 + kk] = *(const short8*)&hs1[ar * 264 + kk * 32 + ac8];
    // layer1(t): [h0(t) | h1(t-1)] @ [wi1; wh1] + b
    f32x4 acc1a = {b1v, b1v, b1v, b1v};
    f32x4 acc1b = {0.f, 0.f, 0.f, 0.f};
#pragma unroll
    for (int kk = 0; kk < 8; kk++) {
      acc1a = __builtin_amdgcn_mfma_f32_16x16x32_f16(a[kk], rw1[kk], acc1a, 0, 0, 0);
      acc1b = __builtin_amdgcn_mfma_f32_16x16x32_f16(a[kk + 8], rw1[kk + 8], acc1b, 0, 0, 0);
    }
    // layer0(t+1): [x(t+1) | h0(t)] @ [wi0; wh0] + b
    f32x4 acc0a = {b0v, b0v, b0v, b0v};
    f32x4 acc0b = {0.f, 0.f, 0.f, 0.f};
    if (t < 255) {
      acc0a = __builtin_amdgcn_mfma_f32_16x16x32_f16(xa0, rw0[0], acc0a, 0, 0, 0);
      acc0b = __builtin_amdgcn_mfma_f32_16x16x32_f16(xa1, rw0[1], acc0b, 0, 0, 0);
      acc0a = __builtin_amdgcn_mfma_f32_16x16x32_f16(xa2, rw0[2], acc0a, 0, 0, 0);
      acc0b = __builtin_amdgcn_mfma_f32_16x16x32_f16(xa3, rw0[3], acc0b, 0, 0, 0);
#pragma unroll
      for (int kk = 0; kk < 8; kk += 2) {
        acc0a = __builtin_amdgcn_mfma_f32_16x16x32_f16(a[kk], rw0[4 + kk], acc0a, 0, 0, 0);
        acc0b = __builtin_amdgcn_mfma_f32_16x16x32_f16(a[kk + 1], rw0[5 + kk], acc0b, 0, 0, 0);
      }
    }
#pragma unroll
    for (int r = 0; r < 4; r++)
      gx[0][wv][(lane >> 4) * 4 + r][ar] = acc1a[r] + acc1b[r];
    if (t < 255) {
#pragma unroll
      for (int r = 0; r < 4; r++)
        gx[1][wv][(lane >> 4) * 4 + r][ar] = acc0a[r] + acc0b[r];
    }
    __syncthreads();  // S2: gates ready
    // cell1 first -> early publish of flagA
    {
      float gi = gx[0][0][cr][cc], gfv = gx[0][1][cr][cc], gg = gx[0][2][cr][cc],
            go = gx[0][3][cr][cc];
      c1 = sigf(gfv) * c1 + sigf(gi) * tanhfast(gg);
      h1v = sigf(go) * tanhfast(c1);
      pack_store(f2h(h1v), h1buf + (t & 1) * 65536 + hrow, lane);
    }
    __syncthreads();  // S3a: h1 stores drained
    if (tid == 0)
      __hip_atomic_store(&flagsA[gb * 16 + gh], t + 1, __ATOMIC_RELAXED,
                         __HIP_MEMORY_SCOPE_AGENT);
    if (t < 255) {
      float gi = gx[1][0][cr][cc], gfv = gx[1][1][cr][cc], gg = gx[1][2][cr][cc],
            go = gx[1][3][cr][cc];
      c0 = sigf(gfv) * c0 + sigf(gi) * tanhfast(gg);
      float h0v = sigf(go) * tanhfast(c0);
      pack_store(f2h(h0v), h0buf + ((t + 1) & 1) * 65536 + hrow, lane);
    }
    __syncthreads();  // S3b: h0 stores drained
    if (tid == 0 && t < 255)
      __hip_atomic_store(&flagsB[gb * 16 + gh], t + 2, __ATOMIC_RELAXED,
                         __HIP_MEMORY_SCOPE_AGENT);
  }
  hfinal[hrow] = h1v;
}

// ---------------- MLP head ----------------
__global__ __launch_bounds__(256, 2) void k_mlp(const float* __restrict__ hfinal,
                                                const float* __restrict__ s,
                                                const float* __restrict__ w1,
                                                const float* __restrict__ b1,
                                                const float* __restrict__ w2,
                                                const float* __restrict__ b2,
                                                const float* __restrict__ wp,
                                                const float* __restrict__ bp,
                                                float* __restrict__ out) {
  __shared__ float feat[257];
  __shared__ float z1[256];
  __shared__ float z2[128];
  const int tid = threadIdx.x, b = blockIdx.x;
  feat[tid] = hfinal[b * 256 + tid];
  if (tid == 0) feat[256] = s[b];
  __syncthreads();
  float a = b1[tid];
  for (int i = 0; i < 257; i++) a += feat[i] * w1[i * 256 + tid];
  z1[tid] = fmaxf(a, 0.f);
  __syncthreads();
  if (tid < 128) {
    float a2 = b2[tid];
    for (int i = 0; i < 256; i++) a2 += z1[i] * w2[i * 128 + tid];
    z2[tid] = fmaxf(a2, 0.f);
  }
  __syncthreads();
  if (tid == 0) {
    float sv = bp[0];
    for (int i = 0; i < 128; i++) sv += z2[i] * wp[i];
    out[b] = fmaxf(sv, 0.f) + log1pf(__expf(-fabsf(sv)));
  }
}

extern "C" void kernel_launch(void* const* d_in, const int* in_sizes, int n_in,
                              void* d_out, int out_size, void* d_ws, size_t ws_size,
                              hipStream_t stream) {
  const float* x = (const float*)d_in[0];
  const float* s = (const float*)d_in[1];
  const float* c1w = (const float*)d_in[2];
  const float* c1b = (const float*)d_in[3];
  const float* bn1g = (const float*)d_in[4];
  const float* bn1b = (const float*)d_in[5];
  const float* c2w = (const float*)d_in[6];
  const float* c2b = (const float*)d_in[7];
  const float* bn2g = (const float*)d_in[8];
  const float* bn2b = (const float*)d_in[9];
  const float* wi0 = (const float*)d_in[10];
  const float* bi0 = (const float*)d_in[11];
  const float* wh0 = (const float*)d_in[12];
  const float* bh0 = (const float*)d_in[13];
  const float* wi1 = (const float*)d_in[14];
  const float* bi1 = (const float*)d_in[15];
  const float* wh1 = (const float*)d_in[16];
  const float* bh1 = (const float*)d_in[17];
  const float* w1 = (const float*)d_in[18];
  const float* b1 = (const float*)d_in[19];
  const float* w2 = (const float*)d_in[20];
  const float* b2 = (const float*)d_in[21];
  const float* wp = (const float*)d_in[22];
  const float* bp = (const float*)d_in[23];

  char* ws = (char*)d_ws;
  int* flagsA = (int*)(ws + OFF_FLAGSA);
  int* flagsB = (int*)(ws + OFF_FLAGSB);
  float* sc1 = (float*)(ws + OFF_SC1);
  float* sh1 = (float*)(ws + OFF_SH1);
  float* sc2 = (float*)(ws + OFF_SC2);
  float* sh2 = (float*)(ws + OFF_SH2);
  float* part1 = (float*)(ws + OFF_PART1);
  float* part2 = (float*)(ws + OFF_PART2);
  unsigned short* w2f = (unsigned short*)(ws + OFF_W2F);
  unsigned short* seq = (unsigned short*)(ws + OFF_SEQ);
  unsigned short* h0b = (unsigned short*)(ws + OFF_H0);
  unsigned short* h1b = (unsigned short*)(ws + OFF_H1);
  float* hf = (float*)(ws + OFF_HF);

  k_init<<<1, 256, 0, stream>>>((u64*)ws);
  k_conv1<<<256, 256, 0, stream>>>(x, c1w, c1b, part1);
  k_bn1<<<64, 256, 0, stream>>>(part1, bn1g, bn1b, sc1, sh1);
  k_w2frag<<<160, 256, 0, stream>>>(c2w, w2f);
  k_conv2<<<256, 256, 0, stream>>>(x, c1w, c1b, sc1, sh1, w2f, c2b, seq, part2);
  k_bn2<<<128, 256, 0, stream>>>(part2, bn2g, bn2b, sc2, sh2);
  k_norm2<<<2048, 256, 0, stream>>>((u64*)seq, sc2, sh2);
  k_lstm<<<256, 256, 0, stream>>>(seq, wi0, bi0, wh0, bh0, wi1, bi1, wh1, bh1,
                                  h0b, h1b, flagsA, flagsB, hf);
  k_mlp<<<256, 256, 0, stream>>>(hf, s, w1, b1, w2, b2, wp, bp, (float*)d_out);
}